// Round 7
// baseline (213.801 us; speedup 1.0000x reference)
//
#include <hip/hip_runtime.h>

// ------- MFMA fp16 LSTM, skewed-layer pipeline, parity-unrolled phases -------
// Phase p computes layer1(t=p) AND layer0(t=p+1) between barriers (29 barriers).
// Round 7: round-5 structure + breadth-first gate math (spill-free per round 6's
// WRITE_SIZE evidence) + __launch_bounds__(512,4) (round 6's (512,2) cost ~1/2 of
// residency) + phase loop unrolled by 2 so plane parity is compile-time: all LDS
// addresses become one persistent VGPR + ds-offset immediate (kills ~20 v_add
// per phase per wave of address arithmetic).
//
// GEMM: C[m=gate(256)][n=batch(32)] = W[m][k] * data[k][n], gate rows permuted
// row'=4*unit+gate so a lane's 4 C-regs = (i,f,g,o) of one unit; c-state in VGPRs.
// Block = 512 thr (8 waves), wave w owns m-tiles {2w,2w+1} x n-tiles {0,1}.
// A (weights) gathered once per block from global fp32 (L2-resident).
// bias0 folded as k=28 constant-1 column; bias1 pre-added into acc init.
// B in LDS frag-linear layout: lane reads 16B at lane*16, conflict-free b128.
// Planes (flat arrays, plane P at P*size): h0(t)->h0p[t&1], h1(t)->h1p[t&1],
// x(t)->xb[t&1].

typedef _Float16 half8 __attribute__((ext_vector_type(8)));
typedef float floatx4 __attribute__((ext_vector_type(4)));

// Breadth-first 4-tile gate batch: acc -> (c update, h write into plane).
__device__ __forceinline__ void gate_batch4(const floatx4 (&acc)[2][2], float (&c)[4],
                                            _Float16* __restrict__ plane,
                                            const int (&hwr)[2][2]) {
    float ei[4], ef[4], eg[4], eo[4];
    #pragma unroll
    for (int tt = 0; tt < 4; ++tt) {
        floatx4 a = acc[tt >> 1][tt & 1];
        ei[tt] = __expf(-a[0]);
        ef[tt] = __expf(-a[1]);
        eg[tt] = __expf(2.0f * a[2]);
        eo[tt] = __expf(-a[3]);
    }
    float ri[4], rf[4], rg[4], ro[4];
    #pragma unroll
    for (int tt = 0; tt < 4; ++tt) {
        ri[tt] = __builtin_amdgcn_rcpf(1.0f + ei[tt]);
        rf[tt] = __builtin_amdgcn_rcpf(1.0f + ef[tt]);
        rg[tt] = __builtin_amdgcn_rcpf(1.0f + eg[tt]);
        ro[tt] = __builtin_amdgcn_rcpf(1.0f + eo[tt]);
    }
    float ec[4];
    #pragma unroll
    for (int tt = 0; tt < 4; ++tt) {
        float tg = 1.0f - 2.0f * rg[tt];
        float cn = rf[tt] * c[tt] + ri[tt] * tg;
        c[tt] = cn;
        ec[tt] = __expf(2.0f * cn);
    }
    #pragma unroll
    for (int tt = 0; tt < 4; ++tt) {
        float tc = 1.0f - 2.0f * __builtin_amdgcn_rcpf(ec[tt] + 1.0f);
        plane[hwr[tt >> 1][tt & 1]] = (_Float16)(ro[tt] * tc);
    }
}

// One interior phase with compile-time parity PR (p & 1 == PR):
//   reads  h0(p)=h0p[PR], h1(p-1)=h1p[PR^1], x(p+1)=xb[PR^1]
//   writes h0(p+1)=h0p[PR^1], h1(p)=h1p[PR], stages x(p+2)->xb[PR]
template <int PR>
__device__ __forceinline__ void interior_phase(
        int xoff, const float* const (&xg)[2], bool xvalid, int xi, const int (&xstg)[2],
        const half8 (&A0)[2][3], const half8 (&A1)[2][4], const floatx4 (&bias1)[2],
        float (&c0)[4], float (&c1)[4],
        const int (&xrd)[2], const int (&hrd)[2][2], const int (&hwr)[2][2],
        _Float16* __restrict__ h0p, _Float16* __restrict__ h1p, _Float16* __restrict__ xb) {
    constexpr int H0R = PR * 2048, H0W = (PR ^ 1) * 2048;
    constexpr int H1R = (PR ^ 1) * 2048, H1W = PR * 2048;
    constexpr int XR = (PR ^ 1) * 1024, XW = PR * 1024;

    // global prefetch x(p+2) first (latency hidden under MFMA/gate section)
    float xn[2] = {0.f, 0.f};
    #pragma unroll
    for (int s = 0; s < 2; ++s)
        if (xvalid) xn[s] = xg[s][xoff];

    // B-fragment loads: bx + bh0 (shared by both GEMMs)
    half8 bx[2], bh0[2][2];
    #pragma unroll
    for (int in = 0; in < 2; ++in) {
        bx[in] = *(const half8*)&xb[XR + xrd[in]];
        #pragma unroll
        for (int kt = 0; kt < 2; ++kt)
            bh0[kt][in] = *(const half8*)&h0p[H0R + hrd[kt][in]];
    }

    floatx4 acc0[2][2], acc1[2][2];
    #pragma unroll
    for (int im = 0; im < 2; ++im)
        #pragma unroll
        for (int in = 0; in < 2; ++in) {
            acc0[im][in] = (floatx4){0.f, 0.f, 0.f, 0.f};
            acc1[im][in] = bias1[im];
        }
    #pragma unroll
    for (int in = 0; in < 2; ++in)
        #pragma unroll
        for (int im = 0; im < 2; ++im)
            acc0[im][in] = __builtin_amdgcn_mfma_f32_16x16x32_f16(A0[im][0], bx[in], acc0[im][in], 0, 0, 0);
    #pragma unroll
    for (int kt = 0; kt < 2; ++kt)
        #pragma unroll
        for (int in = 0; in < 2; ++in)
            #pragma unroll
            for (int im = 0; im < 2; ++im) {
                acc0[im][in] = __builtin_amdgcn_mfma_f32_16x16x32_f16(A0[im][kt + 1], bh0[kt][in], acc0[im][in], 0, 0, 0);
                acc1[im][in] = __builtin_amdgcn_mfma_f32_16x16x32_f16(A1[im][kt],     bh0[kt][in], acc1[im][in], 0, 0, 0);
            }
    // bh1 loaded late (short liveness -> lower register pressure)
    half8 bh1[2][2];
    #pragma unroll
    for (int kt = 0; kt < 2; ++kt)
        #pragma unroll
        for (int in = 0; in < 2; ++in)
            bh1[kt][in] = *(const half8*)&h1p[H1R + hrd[kt][in]];
    #pragma unroll
    for (int kt = 0; kt < 2; ++kt)
        #pragma unroll
        for (int in = 0; in < 2; ++in)
            #pragma unroll
            for (int im = 0; im < 2; ++im)
                acc1[im][in] = __builtin_amdgcn_mfma_f32_16x16x32_f16(A1[im][kt + 2], bh1[kt][in], acc1[im][in], 0, 0, 0);

    gate_batch4(acc0, c0, &h0p[H0W], hwr);   // h0(p+1)
    gate_batch4(acc1, c1, &h1p[H1W], hwr);   // h1(p)

    #pragma unroll
    for (int s = 0; s < 2; ++s)
        xb[XW + xstg[s]] = (xi == 28) ? (_Float16)1.0f : (_Float16)xn[s];
    __syncthreads();
}

__launch_bounds__(512, 4)
__global__ void lstm_mfma(const float* __restrict__ x,
                          const float* __restrict__ Wih0, const float* __restrict__ Whh0,
                          const float* __restrict__ bih0, const float* __restrict__ bhh0,
                          const float* __restrict__ Wih1, const float* __restrict__ Whh1,
                          const float* __restrict__ bih1, const float* __restrict__ bhh1,
                          const float* __restrict__ Wlin, const float* __restrict__ blin,
                          float* __restrict__ out) {
    __shared__ __align__(16) _Float16 h0p[2 * 2048];
    __shared__ __align__(16) _Float16 h1p[2 * 2048];
    __shared__ __align__(16) _Float16 xb[2 * 1024];
    __shared__ float wlin_s[640];
    __shared__ float blin_s[10];

    const int lane = threadIdx.x;
    const int w    = threadIdx.y;          // 0..7
    const int tid  = w * 64 + lane;        // 0..511
    const int quad = lane >> 4;
    const int col  = lane & 15;

    // ---- gather A fragments from global fp32 weights (one-time; L2-resident) ----
    half8 A0[2][3], A1[2][4];
    #pragma unroll
    for (int im = 0; im < 2; ++im) {
        int mt = 2 * w + im;
        int m  = mt * 16 + col;
        int u  = m >> 2, g = m & 3;
        int row = g * 64 + u;                       // original weight row
        #pragma unroll
        for (int kt = 0; kt < 3; ++kt) {
            half8 r;
            #pragma unroll
            for (int j = 0; j < 8; ++j) {
                int k = kt * 32 + quad * 8 + j;
                float v;
                if (k < 28)       v = Wih0[row * 28 + k];
                else if (k == 28) v = bih0[row] + bhh0[row];
                else if (k < 32)  v = 0.f;
                else              v = Whh0[row * 64 + (k - 32)];
                r[j] = (_Float16)v;
            }
            A0[im][kt] = r;
        }
        #pragma unroll
        for (int kt = 0; kt < 4; ++kt) {
            half8 r;
            #pragma unroll
            for (int j = 0; j < 8; ++j) {
                int k = kt * 32 + quad * 8 + j;
                float v = (k < 64) ? Wih1[row * 64 + k] : Whh1[row * 64 + (k - 64)];
                r[j] = (_Float16)v;
            }
            A1[im][kt] = r;
        }
    }
    floatx4 bias1[2];
    #pragma unroll
    for (int im = 0; im < 2; ++im) {
        int u = (2 * w + im) * 4 + quad;
        #pragma unroll
        for (int r = 0; r < 4; ++r) bias1[im][r] = bih1[r * 64 + u] + bhh1[r * 64 + u];
    }

    // ---- t-invariant LDS offsets (halves) ----
    int xrd[2], hrd[2][2], hwr[2][2];
    #pragma unroll
    for (int in = 0; in < 2; ++in) {
        xrd[in] = in * 512 + lane * 8;
        #pragma unroll
        for (int kt = 0; kt < 2; ++kt) hrd[kt][in] = (in * 2 + kt) * 512 + lane * 8;
        #pragma unroll
        for (int im = 0; im < 2; ++im) {
            int u = (2 * w + im) * 4 + quad;
            hwr[im][in] = (in * 2 + (u >> 5)) * 512 + (((u >> 3) & 3) * 16 + col) * 8 + (u & 7);
        }
    }

    // ---- x prefetch: slot s covers b=(tid>>5)+16s, i=tid&31 ----
    const int xi = tid & 31;
    const bool xvalid = xi < 28;
    const float* xg[2];
    int xstg[2];
    #pragma unroll
    for (int s = 0; s < 2; ++s) {
        int b = (tid >> 5) + s * 16;
        xg[s]   = x + (blockIdx.x * 32 + b) * 784 + xi;
        xstg[s] = (b >> 4) * 512 + ((xi >> 3) * 16 + (b & 15)) * 8 + (xi & 7);
    }

    // ---- init: zero h0(-1)=h0p[1], h1(-1)=h1p[1]; stage x(0) into xb[0] ----
    {
        int* z0 = (int*)&h0p[2048];
        int* z1 = (int*)&h1p[2048];
        #pragma unroll
        for (int i = tid; i < 1024; i += 512) { z0[i] = 0; z1[i] = 0; }
        #pragma unroll
        for (int s = 0; s < 2; ++s) {
            float xv = xvalid ? xg[s][0] : 0.f;
            xb[xstg[s]] = (xi == 28) ? (_Float16)1.0f : (_Float16)xv;
        }
    }
    __syncthreads();

    float c0[4] = {0.f, 0.f, 0.f, 0.f};
    float c1[4] = {0.f, 0.f, 0.f, 0.f};

    // ======== prologue phase (p = -1): layer0(t=0) only ========
    {
        float xn[2] = {0.f, 0.f};
        #pragma unroll
        for (int s = 0; s < 2; ++s)
            if (xvalid) xn[s] = xg[s][28];          // x(1)

        floatx4 acc0[2][2];
        #pragma unroll
        for (int im = 0; im < 2; ++im)
            #pragma unroll
            for (int in = 0; in < 2; ++in)
                acc0[im][in] = (floatx4){0.f, 0.f, 0.f, 0.f};
        #pragma unroll
        for (int in = 0; in < 2; ++in) {
            half8 bf = *(const half8*)&xb[xrd[in]];
            #pragma unroll
            for (int im = 0; im < 2; ++im)
                acc0[im][in] = __builtin_amdgcn_mfma_f32_16x16x32_f16(A0[im][0], bf, acc0[im][in], 0, 0, 0);
        }
        #pragma unroll
        for (int kt = 0; kt < 2; ++kt) {
            #pragma unroll
            for (int in = 0; in < 2; ++in) {
                half8 bf = *(const half8*)&h0p[2048 + hrd[kt][in]];   // zeros
                #pragma unroll
                for (int im = 0; im < 2; ++im)
                    acc0[im][in] = __builtin_amdgcn_mfma_f32_16x16x32_f16(A0[im][kt + 1], bf, acc0[im][in], 0, 0, 0);
            }
        }
        gate_batch4(acc0, c0, &h0p[0], hwr);        // h0(0) -> plane 0
        #pragma unroll
        for (int s = 0; s < 2; ++s)                 // stage x(1) -> plane 1
            xb[1024 + xstg[s]] = (xi == 28) ? (_Float16)1.0f : (_Float16)xn[s];
        __syncthreads();
    }

    // ======== main phases p = 0..25 (13 parity-unrolled pairs) ========
    int xoff = 2 * 28;                              // x(p+2) index for p=0
    #pragma unroll 1
    for (int pp = 0; pp < 13; ++pp) {
        interior_phase<0>(xoff,      xg, xvalid, xi, xstg, A0, A1, bias1, c0, c1,
                          xrd, hrd, hwr, h0p, h1p, xb);
        interior_phase<1>(xoff + 28, xg, xvalid, xi, xstg, A0, A1, bias1, c0, c1,
                          xrd, hrd, hwr, h0p, h1p, xb);
        xoff += 56;
    }
    // ---- phase p = 26 (parity 0), x prefetch clamped to x(27) (re-stage, harmless) ----
    interior_phase<0>(27 * 28, xg, xvalid, xi, xstg, A0, A1, bias1, c0, c1,
                      xrd, hrd, hwr, h0p, h1p, xb);

    // ======== final phase (p = 27, parity 1): layer1(t=27) only ========
    {
        floatx4 acc1[2][2];
        #pragma unroll
        for (int im = 0; im < 2; ++im)
            #pragma unroll
            for (int in = 0; in < 2; ++in)
                acc1[im][in] = bias1[im];
        #pragma unroll
        for (int kt = 0; kt < 2; ++kt) {
            #pragma unroll
            for (int in = 0; in < 2; ++in) {
                half8 b0 = *(const half8*)&h0p[2048 + hrd[kt][in]];   // h0(27)
                half8 b1 = *(const half8*)&h1p[hrd[kt][in]];          // h1(26)
                #pragma unroll
                for (int im = 0; im < 2; ++im) {
                    acc1[im][in] = __builtin_amdgcn_mfma_f32_16x16x32_f16(A1[im][kt],     b0, acc1[im][in], 0, 0, 0);
                    acc1[im][in] = __builtin_amdgcn_mfma_f32_16x16x32_f16(A1[im][kt + 2], b1, acc1[im][in], 0, 0, 0);
                }
            }
        }
        gate_batch4(acc1, c1, &h1p[2048], hwr);     // h1(27) -> plane 1
        __syncthreads();
    }

    // ---- epilogue: out = h1(27) @ Wlin^T + blin   (h1(27) in plane 1) ----
    #pragma unroll
    for (int i = tid; i < 640; i += 512) wlin_s[i] = Wlin[i];
    if (tid < 10) blin_s[tid] = blin[tid];
    __syncthreads();
    if (tid < 320) {
        int b = tid / 10, o = tid - b * 10;
        float a = blin_s[o];
        #pragma unroll 8
        for (int u = 0; u < 64; ++u) {
            float hv = (float)h1p[2048 + ((b >> 4) * 2 + (u >> 5)) * 512 + (((u >> 3) & 3) * 16 + (b & 15)) * 8 + (u & 7)];
            a += wlin_s[o * 64 + u] * hv;
        }
        out[(blockIdx.x * 32 + b) * 10 + o] = a;
    }
}

extern "C" void kernel_launch(void* const* d_in, const int* in_sizes, int n_in,
                              void* d_out, int out_size, void* d_ws, size_t ws_size,
                              hipStream_t stream) {
    const float* x    = (const float*)d_in[0];
    const float* Wih0 = (const float*)d_in[1];
    const float* Whh0 = (const float*)d_in[2];
    const float* bih0 = (const float*)d_in[3];
    const float* bhh0 = (const float*)d_in[4];
    const float* Wih1 = (const float*)d_in[5];
    const float* Whh1 = (const float*)d_in[6];
    const float* bih1 = (const float*)d_in[7];
    const float* bhh1 = (const float*)d_in[8];
    const float* Wlin = (const float*)d_in[9];
    const float* blin = (const float*)d_in[10];
    float* out = (float*)d_out;

    lstm_mfma<<<512, dim3(64, 8), 0, stream>>>(x, Wih0, Whh0, bih0, bhh0,
                                               Wih1, Whh1, bih1, bhh1, Wlin, blin, out);
}